// Round 2
// baseline (552.930 us; speedup 1.0000x reference)
//
#include <hip/hip_runtime.h>

#define N_NODES 50000
#define N_EDGES 800000
#define N_GRAPHS 512
#define HIDDEN 256
#define NODE_FEAT 9
#define LAYERS 4
#define BUCKET 64   // max degree capacity (mean 16, max ~35 for uniform random)

typedef float floatx4 __attribute__((ext_vector_type(4)));
typedef short short8 __attribute__((ext_vector_type(8)));

__device__ __forceinline__ float bf2f(unsigned u) {
    unsigned v = u << 16;
    float f;
    __builtin_memcpy(&f, &v, 4);
    return f;
}
__device__ __forceinline__ unsigned short f2bf(float f) {
    unsigned v;
    __builtin_memcpy(&v, &f, 4);
    v += 0x7FFFu + ((v >> 16) & 1u);   // round-to-nearest-even
    return (unsigned short)(v >> 16);
}

// ---------------- one-pass bucketed CSR build ----------------
__global__ void fillb_kernel(const int* __restrict__ src, const int* __restrict__ dst,
                             int* __restrict__ cnt, int* __restrict__ col_src, int E) {
    int e = blockIdx.x * blockDim.x + threadIdx.x;
    if (e < E) {
        int d = dst[e];
        int pos = atomicAdd(&cnt[d], 1);
        if (pos < BUCKET) col_src[d * BUCKET + pos] = src[e];
    }
}

__global__ void dinv_kernel(const int* __restrict__ cnt, float* __restrict__ dinv, int N) {
    int i = blockIdx.x * blockDim.x + threadIdx.x;
    if (i < N) dinv[i] = rsqrtf((float)(cnt[i] + 1));   // +1 self loop
}

// ---------------- graph boundary search (batch is sorted) ----------------
__global__ void findstart_kernel(const int* __restrict__ batch, int* __restrict__ gstart) {
    int g = blockIdx.x * blockDim.x + threadIdx.x;
    if (g > N_GRAPHS) return;
    if (g == N_GRAPHS) { gstart[g] = N_NODES; return; }
    int lo = 0, hi = N_NODES;
    while (lo < hi) {
        int mid = (lo + hi) >> 1;
        if (batch[mid] < g) lo = mid + 1; else hi = mid;
    }
    gstart[g] = lo;   // first node with batch[n] >= g
}

// ---------------- W pre-pack into MFMA B-fragment layout (bf16) ----------------
__global__ __launch_bounds__(256) void packW_kernel(const float* __restrict__ W,
                                                    unsigned short* __restrict__ Wsw) {
    int idx = blockIdx.x * 256 + threadIdx.x;   // 0..32767
    int lane = idx & 63;
    int ct   = (idx >> 6) & 15;
    int ks   = (idx >> 10) & 7;
    int l    = idx >> 13;
    int n = ct * 16 + (lane & 15);
    int kbase = ks * 32 + (lane >> 4) * 8;
    const float* Wl = W + (size_t)l * HIDDEN * HIDDEN;
    alignas(16) unsigned short tmp[8];
    #pragma unroll
    for (int j = 0; j < 8; j++)
        tmp[j] = f2bf(Wl[(size_t)(kbase + j) * HIDDEN + n]);
    *(uint4*)&Wsw[(size_t)idx * 8] = *(const uint4*)tmp;
}

// ---------------- embed: h = relu(x @ embW + embb), bf16 out ----------------
__global__ __launch_bounds__(256) void embed_kernel(const float* __restrict__ x,
                                                    const float* __restrict__ W,
                                                    const float* __restrict__ b,
                                                    unsigned short* __restrict__ h) {
    int n = blockIdx.x;
    int c = threadIdx.x;
    float acc = b[c];
    #pragma unroll
    for (int k = 0; k < NODE_FEAT; k++)
        acc += x[n * NODE_FEAT + k] * W[k * HIDDEN + c];
    h[(size_t)n * HIDDEN + c] = f2bf(fmaxf(acc, 0.0f));
}

// ---------------- hw = h @ W  (bf16 MFMA; depth-2 W prefetch) ----------------
__global__ __launch_bounds__(256, 2) void gemm_mfma(const unsigned short* __restrict__ hin,
                                                    const unsigned short* __restrict__ Wsw,
                                                    unsigned short* __restrict__ hwout, int N) {
    __shared__ unsigned short As[64][264];   // +8 pad; reused as C-buffer in epilogue
    int t = threadIdx.x;
    int wv = t >> 6, lane = t & 63, quad = lane >> 4, l15 = lane & 15;
    int n0 = blockIdx.x * 64;
    const uint4* h4 = (const uint4*)hin;     // 32 uint4 per row

    uint4 av[8];
    #pragma unroll
    for (int i = 0; i < 8; i++) {
        int j = t + i * 256;
        int r = j >> 5;
        int c = j & 31;
        int n = n0 + r;
        av[i] = make_uint4(0u, 0u, 0u, 0u);
        if (n < N) av[i] = h4[(size_t)n * 32 + c];
    }
    const short8* Wl = (const short8*)Wsw;
    short8 bq[3][4];
    #pragma unroll
    for (int p = 0; p < 2; p++)
        #pragma unroll
        for (int ci = 0; ci < 4; ci++)
            bq[p][ci] = Wl[(size_t)(p * 16 + wv * 4 + ci) * 64 + lane];
    #pragma unroll
    for (int i = 0; i < 8; i++) {
        int j = t + i * 256;
        int r = j >> 5;
        int c = j & 31;
        *(uint4*)&As[r][c * 8] = av[i];
    }
    __syncthreads();

    floatx4 acc[4][4];
    #pragma unroll
    for (int i = 0; i < 4; i++)
        #pragma unroll
        for (int j = 0; j < 4; j++)
            acc[i][j] = (floatx4){0.f, 0.f, 0.f, 0.f};

    #pragma unroll
    for (int ks = 0; ks < 8; ks++) {
        if (ks < 6) {
            #pragma unroll
            for (int ci = 0; ci < 4; ci++)
                bq[(ks + 2) % 3][ci] = Wl[(size_t)((ks + 2) * 16 + wv * 4 + ci) * 64 + lane];
        }
        short8 a[4];
        #pragma unroll
        for (int rt = 0; rt < 4; rt++)
            a[rt] = *(const short8*)&As[rt * 16 + l15][ks * 32 + quad * 8];
        #pragma unroll
        for (int rt = 0; rt < 4; rt++)
            #pragma unroll
            for (int ci = 0; ci < 4; ci++)
                acc[rt][ci] = __builtin_amdgcn_mfma_f32_16x16x32_bf16(a[rt], bq[ks % 3][ci], acc[rt][ci], 0, 0, 0);
    }

    __syncthreads();   // all A-fragment reads done
    #pragma unroll
    for (int rt = 0; rt < 4; rt++) {
        #pragma unroll
        for (int ci = 0; ci < 4; ci++) {
            int col = (wv * 4 + ci) * 16 + l15;
            int rowb = rt * 16 + quad * 4;
            #pragma unroll
            for (int reg = 0; reg < 4; reg++)
                As[rowb + reg][col] = f2bf(acc[rt][ci][reg]);
        }
    }
    __syncthreads();
    #pragma unroll
    for (int i = 0; i < 8; i++) {
        int j = t + i * 256;
        int r = j >> 5;
        int c = j & 31;
        int n = n0 + r;
        if (n < N)
            *(uint4*)&hwout[(size_t)n * HIDDEN + c * 8] = *(const uint4*)&As[r][c * 8];
    }
}

__device__ __forceinline__ void acc8(float* a, uint4 u, float nr) {
    a[0] += nr * bf2f(u.x & 0xFFFFu); a[1] += nr * bf2f(u.x >> 16);
    a[2] += nr * bf2f(u.y & 0xFFFFu); a[3] += nr * bf2f(u.y >> 16);
    a[4] += nr * bf2f(u.z & 0xFFFFu); a[5] += nr * bf2f(u.z >> 16);
    a[6] += nr * bf2f(u.w & 0xFFFFu); a[7] += nr * bf2f(u.w >> 16);
}

// ---------------- fused agg_l + gemm_{l+1} ----------------
// Block owns 64 dst nodes. Phase A: 8 passes, each half-wave (32 lanes, 8
// cols/lane) gathers one node's messages from hw_l (globally complete),
// adds self+bias, relu, packs bf16 row straight into the LDS A-tile.
// h_l never touches global memory. Phase B: MFMA transform by W_{l+1}.
// The MFMA/W-load work hides under the fabric-walled gather of other blocks.
__global__ __launch_bounds__(256) void fused_agg_gemm(
        const unsigned short* __restrict__ hw,
        const int* __restrict__ cnt, const int* __restrict__ col_src,
        const float* __restrict__ dinv, const float* __restrict__ bias,
        const unsigned short* __restrict__ Wsw,
        unsigned short* __restrict__ hwout, int N) {
    __shared__ unsigned short As[64][264];
    __shared__ uint2 sEdge[4][2][BUCKET];
    int t = threadIdx.x;
    int wv = t >> 6, lane = t & 63, quad = lane >> 4, l15 = lane & 15;
    int half = lane >> 5, q = lane & 31;
    int n0 = blockIdx.x * 64;
    const uint4* hw4 = (const uint4*)hw;

    float4 b0 = *(const float4*)&bias[8 * q];
    float4 b1 = *(const float4*)&bias[8 * q + 4];

    // ---- phase A: aggregate 64 rows into As ----
    #pragma unroll 1
    for (int p = 0; p < 8; p++) {
        int r = p * 8 + wv * 2 + half;
        int n = n0 + r;
        unsigned r0 = 0, r1 = 0, r2 = 0, r3 = 0;
        if (n < N) {
            float dn = dinv[n];
            int deg = cnt[n]; if (deg > BUCKET) deg = BUCKET;
            if (q < deg) {
                int s = col_src[n * BUCKET + q];
                float nr = dinv[s] * dn;
                unsigned nrb; __builtin_memcpy(&nrb, &nr, 4);
                sEdge[wv][half][q] = make_uint2((unsigned)s, nrb);
            }
            if (q + 32 < deg) {
                int s = col_src[n * BUCKET + q + 32];
                float nr = dinv[s] * dn;
                unsigned nrb; __builtin_memcpy(&nrb, &nr, 4);
                sEdge[wv][half][q + 32] = make_uint2((unsigned)s, nrb);
            }
            uint4 s4 = hw4[(size_t)n * 32 + q];
            float selfc = dn * dn;
            float a[8];
            a[0] = bf2f(s4.x & 0xFFFFu) * selfc + b0.x;
            a[1] = bf2f(s4.x >> 16)     * selfc + b0.y;
            a[2] = bf2f(s4.y & 0xFFFFu) * selfc + b0.z;
            a[3] = bf2f(s4.y >> 16)     * selfc + b0.w;
            a[4] = bf2f(s4.z & 0xFFFFu) * selfc + b1.x;
            a[5] = bf2f(s4.z >> 16)     * selfc + b1.y;
            a[6] = bf2f(s4.w & 0xFFFFu) * selfc + b1.z;
            a[7] = bf2f(s4.w >> 16)     * selfc + b1.w;
            int i = 0;
            for (; i + 4 <= deg; i += 4) {
                uint2 p0 = sEdge[wv][half][i];
                uint2 p1 = sEdge[wv][half][i + 1];
                uint2 p2 = sEdge[wv][half][i + 2];
                uint2 p3 = sEdge[wv][half][i + 3];
                uint4 u0 = hw4[(size_t)p0.x * 32 + q];
                uint4 u1 = hw4[(size_t)p1.x * 32 + q];
                uint4 u2 = hw4[(size_t)p2.x * 32 + q];
                uint4 u3 = hw4[(size_t)p3.x * 32 + q];
                float nr0, nr1, nr2, nr3;
                __builtin_memcpy(&nr0, &p0.y, 4);
                __builtin_memcpy(&nr1, &p1.y, 4);
                __builtin_memcpy(&nr2, &p2.y, 4);
                __builtin_memcpy(&nr3, &p3.y, 4);
                acc8(a, u0, nr0); acc8(a, u1, nr1);
                acc8(a, u2, nr2); acc8(a, u3, nr3);
            }
            for (; i < deg; i++) {
                uint2 pe = sEdge[wv][half][i];
                uint4 u = hw4[(size_t)pe.x * 32 + q];
                float nr; __builtin_memcpy(&nr, &pe.y, 4);
                acc8(a, u, nr);
            }
            r0 = (unsigned)f2bf(fmaxf(a[0], 0.0f)) | ((unsigned)f2bf(fmaxf(a[1], 0.0f)) << 16);
            r1 = (unsigned)f2bf(fmaxf(a[2], 0.0f)) | ((unsigned)f2bf(fmaxf(a[3], 0.0f)) << 16);
            r2 = (unsigned)f2bf(fmaxf(a[4], 0.0f)) | ((unsigned)f2bf(fmaxf(a[5], 0.0f)) << 16);
            r3 = (unsigned)f2bf(fmaxf(a[6], 0.0f)) | ((unsigned)f2bf(fmaxf(a[7], 0.0f)) << 16);
        }
        *(uint4*)&As[r][q * 8] = make_uint4(r0, r1, r2, r3);
    }

    // prime 2-deep W prefetch while waiting at barrier
    const short8* Wl = (const short8*)Wsw;
    short8 bq[3][4];
    #pragma unroll
    for (int p = 0; p < 2; p++)
        #pragma unroll
        for (int ci = 0; ci < 4; ci++)
            bq[p][ci] = Wl[(size_t)(p * 16 + wv * 4 + ci) * 64 + lane];
    __syncthreads();

    // ---- phase B: MFMA ----
    floatx4 acc[4][4];
    #pragma unroll
    for (int i = 0; i < 4; i++)
        #pragma unroll
        for (int j = 0; j < 4; j++)
            acc[i][j] = (floatx4){0.f, 0.f, 0.f, 0.f};

    #pragma unroll
    for (int ks = 0; ks < 8; ks++) {
        if (ks < 6) {
            #pragma unroll
            for (int ci = 0; ci < 4; ci++)
                bq[(ks + 2) % 3][ci] = Wl[(size_t)((ks + 2) * 16 + wv * 4 + ci) * 64 + lane];
        }
        short8 a[4];
        #pragma unroll
        for (int rt = 0; rt < 4; rt++)
            a[rt] = *(const short8*)&As[rt * 16 + l15][ks * 32 + quad * 8];
        #pragma unroll
        for (int rt = 0; rt < 4; rt++)
            #pragma unroll
            for (int ci = 0; ci < 4; ci++)
                acc[rt][ci] = __builtin_amdgcn_mfma_f32_16x16x32_bf16(a[rt], bq[ks % 3][ci], acc[rt][ci], 0, 0, 0);
    }

    __syncthreads();   // all A reads done; reuse As as C-buffer
    #pragma unroll
    for (int rt = 0; rt < 4; rt++) {
        #pragma unroll
        for (int ci = 0; ci < 4; ci++) {
            int col = (wv * 4 + ci) * 16 + l15;
            int rowb = rt * 16 + quad * 4;
            #pragma unroll
            for (int reg = 0; reg < 4; reg++)
                As[rowb + reg][col] = f2bf(acc[rt][ci][reg]);
        }
    }
    __syncthreads();
    #pragma unroll
    for (int i = 0; i < 8; i++) {
        int j = t + i * 256;
        int r = j >> 5;
        int c = j & 31;
        int n = n0 + r;
        if (n < N)
            *(uint4*)&hwout[(size_t)n * HIDDEN + c * 8] = *(const uint4*)&As[r][c * 8];
    }
}

// ---------------- fused final agg + pool: per-node dot, atomic per graph ----------------
__global__ __launch_bounds__(256) void agg_pool_kernel(
        const unsigned short* __restrict__ hw,
        const int* __restrict__ cnt, const int* __restrict__ col_src,
        const float* __restrict__ dinv, const float* __restrict__ bias,
        const int* __restrict__ batch, const float* __restrict__ outW,
        float* __restrict__ gsum) {
    __shared__ uint2 sEdge[4][2][BUCKET];
    int wv = threadIdx.x >> 6, lane = threadIdx.x & 63;
    int half = lane >> 5, q = lane & 31;
    int n = blockIdx.x * 8 + wv * 2 + half;
    if (n >= N_NODES) return;
    float dn = dinv[n];
    int deg = cnt[n]; if (deg > BUCKET) deg = BUCKET;

    if (q < deg) {
        int s = col_src[n * BUCKET + q];
        float nr = dinv[s] * dn;
        unsigned nrb; __builtin_memcpy(&nrb, &nr, 4);
        sEdge[wv][half][q] = make_uint2((unsigned)s, nrb);
    }
    if (q + 32 < deg) {
        int s = col_src[n * BUCKET + q + 32];
        float nr = dinv[s] * dn;
        unsigned nrb; __builtin_memcpy(&nrb, &nr, 4);
        sEdge[wv][half][q + 32] = make_uint2((unsigned)s, nrb);
    }

    const uint4* hw4 = (const uint4*)hw;
    uint4 s4 = hw4[(size_t)n * 32 + q];
    float selfc = dn * dn;
    float4 b0 = *(const float4*)&bias[8 * q];
    float4 b1 = *(const float4*)&bias[8 * q + 4];
    float a[8];
    a[0] = bf2f(s4.x & 0xFFFFu) * selfc + b0.x;
    a[1] = bf2f(s4.x >> 16)     * selfc + b0.y;
    a[2] = bf2f(s4.y & 0xFFFFu) * selfc + b0.z;
    a[3] = bf2f(s4.y >> 16)     * selfc + b0.w;
    a[4] = bf2f(s4.z & 0xFFFFu) * selfc + b1.x;
    a[5] = bf2f(s4.z >> 16)     * selfc + b1.y;
    a[6] = bf2f(s4.w & 0xFFFFu) * selfc + b1.z;
    a[7] = bf2f(s4.w >> 16)     * selfc + b1.w;

    int i = 0;
    for (; i + 4 <= deg; i += 4) {
        uint2 p0 = sEdge[wv][half][i];
        uint2 p1 = sEdge[wv][half][i + 1];
        uint2 p2 = sEdge[wv][half][i + 2];
        uint2 p3 = sEdge[wv][half][i + 3];
        uint4 u0 = hw4[(size_t)p0.x * 32 + q];
        uint4 u1 = hw4[(size_t)p1.x * 32 + q];
        uint4 u2 = hw4[(size_t)p2.x * 32 + q];
        uint4 u3 = hw4[(size_t)p3.x * 32 + q];
        float nr0, nr1, nr2, nr3;
        __builtin_memcpy(&nr0, &p0.y, 4);
        __builtin_memcpy(&nr1, &p1.y, 4);
        __builtin_memcpy(&nr2, &p2.y, 4);
        __builtin_memcpy(&nr3, &p3.y, 4);
        acc8(a, u0, nr0); acc8(a, u1, nr1);
        acc8(a, u2, nr2); acc8(a, u3, nr3);
    }
    for (; i < deg; i++) {
        uint2 pe = sEdge[wv][half][i];
        uint4 u = hw4[(size_t)pe.x * 32 + q];
        float nr; __builtin_memcpy(&nr, &pe.y, 4);
        acc8(a, u, nr);
    }

    // h4[n] = relu(a); per-node dot with outW, reduce across the 32-lane half
    float4 w0 = *(const float4*)&outW[8 * q];
    float4 w1 = *(const float4*)&outW[8 * q + 4];
    float dot = fmaxf(a[0], 0.0f) * w0.x + fmaxf(a[1], 0.0f) * w0.y
              + fmaxf(a[2], 0.0f) * w0.z + fmaxf(a[3], 0.0f) * w0.w
              + fmaxf(a[4], 0.0f) * w1.x + fmaxf(a[5], 0.0f) * w1.y
              + fmaxf(a[6], 0.0f) * w1.z + fmaxf(a[7], 0.0f) * w1.w;
    #pragma unroll
    for (int off = 16; off > 0; off >>= 1) dot += __shfl_xor(dot, off, 64);
    if (q == 0) atomicAdd(&gsum[batch[n]], dot);
}

__global__ void finalize_kernel(const float* __restrict__ gsum,
                                const int* __restrict__ gstart,
                                const float* __restrict__ outb,
                                float* __restrict__ out) {
    int g = blockIdx.x * blockDim.x + threadIdx.x;
    if (g < N_GRAPHS) {
        float c = (float)(gstart[g + 1] - gstart[g]);
        out[g] = gsum[g] / fmaxf(c, 1.0f) + outb[0];
    }
}

extern "C" void kernel_launch(void* const* d_in, const int* in_sizes, int n_in,
                              void* d_out, int out_size, void* d_ws, size_t ws_size,
                              hipStream_t stream) {
    const float* x     = (const float*)d_in[0];
    const int*   edge  = (const int*)d_in[1];
    const int*   src   = edge;
    const int*   dst   = edge + N_EDGES;
    const int*   batch = (const int*)d_in[2];
    const float* embW  = (const float*)d_in[3];
    const float* embb  = (const float*)d_in[4];
    const float* convW = (const float*)d_in[5];
    const float* convb = (const float*)d_in[6];
    const float* outW  = (const float*)d_in[7];
    const float* outb  = (const float*)d_in[8];
    float* out = (float*)d_out;

    // workspace layout
    char* ws = (char*)d_ws;
    size_t off = 0;
    auto take = [&](size_t bytes) { char* p = ws + off; off += (bytes + 255) & ~(size_t)255; return p; };
    int*   cnt     = (int*)  take((size_t)N_NODES * 4);
    int*   col_src = (int*)  take((size_t)N_NODES * BUCKET * 4);           // 12.8 MB buckets
    float* dinv    = (float*)take((size_t)N_NODES * 4);
    int*   gstart  = (int*)  take((size_t)(N_GRAPHS + 1) * 4);
    float* gsum    = (float*)take((size_t)N_GRAPHS * 4);
    unsigned short* Wsw = (unsigned short*)take((size_t)LAYERS * 8 * 16 * 64 * 8 * 2); // 512 KB
    unsigned short* h0  = (unsigned short*)take((size_t)N_NODES * HIDDEN * 2);
    unsigned short* h1  = (unsigned short*)take((size_t)N_NODES * HIDDEN * 2);

    hipMemsetAsync(cnt, 0, (size_t)N_NODES * 4, stream);
    hipMemsetAsync(gsum, 0, (size_t)N_GRAPHS * 4, stream);

    fillb_kernel<<<(N_EDGES + 255) / 256, 256, 0, stream>>>(src, dst, cnt, col_src, N_EDGES);
    dinv_kernel<<<(N_NODES + 255) / 256, 256, 0, stream>>>(cnt, dinv, N_NODES);
    findstart_kernel<<<3, 256, 0, stream>>>(batch, gstart);

    packW_kernel<<<128, 256, 0, stream>>>(convW, Wsw);
    embed_kernel<<<N_NODES, 256, 0, stream>>>(x, embW, embb, h0);

    int nblk = (N_NODES + 63) / 64;
    // layer 1 transform: h0 @ W1 -> h1
    gemm_mfma<<<nblk, 256, 0, stream>>>(h0, Wsw, h1, N_NODES);
    // fused agg_l + gemm_{l+1}: h never hits global
    fused_agg_gemm<<<nblk, 256, 0, stream>>>(h1, cnt, col_src, dinv, convb + 0 * HIDDEN,
                                             Wsw + (size_t)1 * 65536, h0, N_NODES);
    fused_agg_gemm<<<nblk, 256, 0, stream>>>(h0, cnt, col_src, dinv, convb + 1 * HIDDEN,
                                             Wsw + (size_t)2 * 65536, h1, N_NODES);
    fused_agg_gemm<<<nblk, 256, 0, stream>>>(h1, cnt, col_src, dinv, convb + 2 * HIDDEN,
                                             Wsw + (size_t)3 * 65536, h0, N_NODES);
    // final layer: agg + pool fused (per-node dot, atomic per graph)
    agg_pool_kernel<<<(N_NODES + 7) / 8, 256, 0, stream>>>(h0, cnt, col_src, dinv,
                                                           convb + 3 * HIDDEN, batch, outW, gsum);
    finalize_kernel<<<2, 256, 0, stream>>>(gsum, gstart, outb, out);
}

// Round 3
// 436.040 us; speedup vs baseline: 1.2681x; 1.2681x over previous
//
#include <hip/hip_runtime.h>

#define N_NODES 50000
#define N_EDGES 800000
#define N_GRAPHS 512
#define HIDDEN 256
#define NODE_FEAT 9
#define LAYERS 4
#define BUCKET 64   // max degree capacity (mean 16, max ~35 for uniform random)

typedef float floatx4 __attribute__((ext_vector_type(4)));
typedef short short8 __attribute__((ext_vector_type(8)));
typedef unsigned uint2v __attribute__((ext_vector_type(2)));

__device__ __forceinline__ float bf2f(unsigned u) {
    unsigned v = u << 16;
    float f;
    __builtin_memcpy(&f, &v, 4);
    return f;
}
__device__ __forceinline__ unsigned short f2bf(float f) {
    unsigned v;
    __builtin_memcpy(&v, &f, 4);
    v += 0x7FFFu + ((v >> 16) & 1u);   // round-to-nearest-even
    return (unsigned short)(v >> 16);
}

// ---------------- one-pass bucketed CSR build ----------------
__global__ void fillb_kernel(const int* __restrict__ src, const int* __restrict__ dst,
                             int* __restrict__ cnt, int* __restrict__ col_src, int E) {
    int e = blockIdx.x * blockDim.x + threadIdx.x;
    if (e < E) {
        int d = dst[e];
        int pos = atomicAdd(&cnt[d], 1);
        if (pos < BUCKET) col_src[d * BUCKET + pos] = src[e];
    }
}

__global__ void dinv_kernel(const int* __restrict__ cnt, float* __restrict__ dinv, int N) {
    int i = blockIdx.x * blockDim.x + threadIdx.x;
    if (i < N) dinv[i] = rsqrtf((float)(cnt[i] + 1));   // +1 self loop
}

// ---------------- graph boundary search (batch is sorted) ----------------
__global__ void findstart_kernel(const int* __restrict__ batch, int* __restrict__ gstart) {
    int g = blockIdx.x * blockDim.x + threadIdx.x;
    if (g > N_GRAPHS) return;
    if (g == N_GRAPHS) { gstart[g] = N_NODES; return; }
    int lo = 0, hi = N_NODES;
    while (lo < hi) {
        int mid = (lo + hi) >> 1;
        if (batch[mid] < g) lo = mid + 1; else hi = mid;
    }
    gstart[g] = lo;   // first node with batch[n] >= g
}

// ---------------- W pre-pack into MFMA B-fragment layout (bf16) ----------------
__global__ __launch_bounds__(256) void packW_kernel(const float* __restrict__ W,
                                                    unsigned short* __restrict__ Wsw) {
    int idx = blockIdx.x * 256 + threadIdx.x;   // 0..32767
    int lane = idx & 63;
    int ct   = (idx >> 6) & 15;
    int ks   = (idx >> 10) & 7;
    int l    = idx >> 13;
    int n = ct * 16 + (lane & 15);
    int kbase = ks * 32 + (lane >> 4) * 8;
    const float* Wl = W + (size_t)l * HIDDEN * HIDDEN;
    alignas(16) unsigned short tmp[8];
    #pragma unroll
    for (int j = 0; j < 8; j++)
        tmp[j] = f2bf(Wl[(size_t)(kbase + j) * HIDDEN + n]);
    *(uint4*)&Wsw[(size_t)idx * 8] = *(const uint4*)tmp;
}

// ---------------- fused embed + gemm1: As-tile computed from x on the fly ----------------
// h0 = relu(x @ embW + embb) is computed in fp32 registers, bf16-rounded into the
// LDS A-tile (identical arithmetic to the old embed kernel), then transformed by
// W0 via MFMA. The 51 MB h0 global round-trip and the embed dispatch disappear.
__global__ __launch_bounds__(256, 2) void embed_gemm(const float* __restrict__ x,
                                                     const float* __restrict__ embW,
                                                     const float* __restrict__ embb,
                                                     const unsigned short* __restrict__ Wsw,
                                                     unsigned short* __restrict__ hwout, int N) {
    __shared__ unsigned short As[64][264];   // +8 pad; reused as C-buffer in epilogue
    int t = threadIdx.x;
    int wv = t >> 6, lane = t & 63, quad = lane >> 4, l15 = lane & 15;
    int n0 = blockIdx.x * 64;

    // prime 2-deep W prefetch (independent of embed compute)
    const short8* Wl = (const short8*)Wsw;
    short8 bq[3][4];
    #pragma unroll
    for (int p = 0; p < 2; p++)
        #pragma unroll
        for (int ci = 0; ci < 4; ci++)
            bq[p][ci] = Wl[(size_t)(p * 16 + wv * 4 + ci) * 64 + lane];

    // compute embed tile -> As. thread (i) handles row r, col-octet c8.
    #pragma unroll 2
    for (int i = 0; i < 8; i++) {
        int j = t + i * 256;
        int r = j >> 5;
        int c8 = j & 31;
        int n = n0 + r;
        unsigned o0 = 0, o1 = 0, o2 = 0, o3 = 0;
        if (n < N) {
            float xr[NODE_FEAT];
            #pragma unroll
            for (int k = 0; k < NODE_FEAT; k++) xr[k] = x[(size_t)n * NODE_FEAT + k];
            float4 a0 = *(const float4*)&embb[c8 * 8];
            float4 a1 = *(const float4*)&embb[c8 * 8 + 4];
            #pragma unroll
            for (int k = 0; k < NODE_FEAT; k++) {
                float4 w0 = *(const float4*)&embW[k * HIDDEN + c8 * 8];
                float4 w1 = *(const float4*)&embW[k * HIDDEN + c8 * 8 + 4];
                a0.x += xr[k] * w0.x; a0.y += xr[k] * w0.y;
                a0.z += xr[k] * w0.z; a0.w += xr[k] * w0.w;
                a1.x += xr[k] * w1.x; a1.y += xr[k] * w1.y;
                a1.z += xr[k] * w1.z; a1.w += xr[k] * w1.w;
            }
            o0 = (unsigned)f2bf(fmaxf(a0.x, 0.f)) | ((unsigned)f2bf(fmaxf(a0.y, 0.f)) << 16);
            o1 = (unsigned)f2bf(fmaxf(a0.z, 0.f)) | ((unsigned)f2bf(fmaxf(a0.w, 0.f)) << 16);
            o2 = (unsigned)f2bf(fmaxf(a1.x, 0.f)) | ((unsigned)f2bf(fmaxf(a1.y, 0.f)) << 16);
            o3 = (unsigned)f2bf(fmaxf(a1.z, 0.f)) | ((unsigned)f2bf(fmaxf(a1.w, 0.f)) << 16);
        }
        *(uint4*)&As[r][c8 * 8] = make_uint4(o0, o1, o2, o3);
    }
    __syncthreads();

    floatx4 acc[4][4];
    #pragma unroll
    for (int i = 0; i < 4; i++)
        #pragma unroll
        for (int j = 0; j < 4; j++)
            acc[i][j] = (floatx4){0.f, 0.f, 0.f, 0.f};

    #pragma unroll
    for (int ks = 0; ks < 8; ks++) {
        if (ks < 6) {
            #pragma unroll
            for (int ci = 0; ci < 4; ci++)
                bq[(ks + 2) % 3][ci] = Wl[(size_t)((ks + 2) * 16 + wv * 4 + ci) * 64 + lane];
        }
        short8 a[4];
        #pragma unroll
        for (int rt = 0; rt < 4; rt++)
            a[rt] = *(const short8*)&As[rt * 16 + l15][ks * 32 + quad * 8];
        #pragma unroll
        for (int rt = 0; rt < 4; rt++)
            #pragma unroll
            for (int ci = 0; ci < 4; ci++)
                acc[rt][ci] = __builtin_amdgcn_mfma_f32_16x16x32_bf16(a[rt], bq[ks % 3][ci], acc[rt][ci], 0, 0, 0);
    }

    __syncthreads();   // all A-fragment reads done; reuse As as C-buffer
    #pragma unroll
    for (int rt = 0; rt < 4; rt++) {
        #pragma unroll
        for (int ci = 0; ci < 4; ci++) {
            int col = (wv * 4 + ci) * 16 + l15;
            int rowb = rt * 16 + quad * 4;
            #pragma unroll
            for (int reg = 0; reg < 4; reg++)
                As[rowb + reg][col] = f2bf(acc[rt][ci][reg]);
        }
    }
    __syncthreads();
    #pragma unroll
    for (int i = 0; i < 8; i++) {
        int j = t + i * 256;
        int r = j >> 5;
        int c = j & 31;
        int n = n0 + r;
        if (n < N)
            *(uint4*)&hwout[(size_t)n * HIDDEN + c * 8] = *(const uint4*)&As[r][c * 8];
    }
}

// ---------------- hw = h @ W  (bf16 MFMA; depth-2 W prefetch, proven) ----------------
__global__ __launch_bounds__(256, 2) void gemm_mfma(const unsigned short* __restrict__ hin,
                                                    const unsigned short* __restrict__ Wsw,
                                                    unsigned short* __restrict__ hwout, int N) {
    __shared__ unsigned short As[64][264];
    int t = threadIdx.x;
    int wv = t >> 6, lane = t & 63, quad = lane >> 4, l15 = lane & 15;
    int n0 = blockIdx.x * 64;
    const uint4* h4 = (const uint4*)hin;

    uint4 av[8];
    #pragma unroll
    for (int i = 0; i < 8; i++) {
        int j = t + i * 256;
        int r = j >> 5;
        int c = j & 31;
        int n = n0 + r;
        av[i] = make_uint4(0u, 0u, 0u, 0u);
        if (n < N) av[i] = h4[(size_t)n * 32 + c];
    }
    const short8* Wl = (const short8*)Wsw;
    short8 bq[3][4];
    #pragma unroll
    for (int p = 0; p < 2; p++)
        #pragma unroll
        for (int ci = 0; ci < 4; ci++)
            bq[p][ci] = Wl[(size_t)(p * 16 + wv * 4 + ci) * 64 + lane];
    #pragma unroll
    for (int i = 0; i < 8; i++) {
        int j = t + i * 256;
        int r = j >> 5;
        int c = j & 31;
        *(uint4*)&As[r][c * 8] = av[i];
    }
    __syncthreads();

    floatx4 acc[4][4];
    #pragma unroll
    for (int i = 0; i < 4; i++)
        #pragma unroll
        for (int j = 0; j < 4; j++)
            acc[i][j] = (floatx4){0.f, 0.f, 0.f, 0.f};

    #pragma unroll
    for (int ks = 0; ks < 8; ks++) {
        if (ks < 6) {
            #pragma unroll
            for (int ci = 0; ci < 4; ci++)
                bq[(ks + 2) % 3][ci] = Wl[(size_t)((ks + 2) * 16 + wv * 4 + ci) * 64 + lane];
        }
        short8 a[4];
        #pragma unroll
        for (int rt = 0; rt < 4; rt++)
            a[rt] = *(const short8*)&As[rt * 16 + l15][ks * 32 + quad * 8];
        #pragma unroll
        for (int rt = 0; rt < 4; rt++)
            #pragma unroll
            for (int ci = 0; ci < 4; ci++)
                acc[rt][ci] = __builtin_amdgcn_mfma_f32_16x16x32_bf16(a[rt], bq[ks % 3][ci], acc[rt][ci], 0, 0, 0);
    }

    __syncthreads();
    #pragma unroll
    for (int rt = 0; rt < 4; rt++) {
        #pragma unroll
        for (int ci = 0; ci < 4; ci++) {
            int col = (wv * 4 + ci) * 16 + l15;
            int rowb = rt * 16 + quad * 4;
            #pragma unroll
            for (int reg = 0; reg < 4; reg++)
                As[rowb + reg][col] = f2bf(acc[rt][ci][reg]);
        }
    }
    __syncthreads();
    #pragma unroll
    for (int i = 0; i < 8; i++) {
        int j = t + i * 256;
        int r = j >> 5;
        int c = j & 31;
        int n = n0 + r;
        if (n < N)
            *(uint4*)&hwout[(size_t)n * HIDDEN + c * 8] = *(const uint4*)&As[r][c * 8];
    }
}

// ---------------- aggregation: wave-per-node, 4 cols/lane (R0 proven 59.2us) ----------------
// Output stored non-temporally: keeps the gathered hw array resident in L2
// (the next consumer reads hout streaming and doesn't need L2 retention).
__global__ __launch_bounds__(256) void agg_kernel(const unsigned short* __restrict__ hw,
                                                  const int* __restrict__ cnt,
                                                  const int* __restrict__ col_src,
                                                  const float* __restrict__ dinv,
                                                  const float* __restrict__ bias,
                                                  unsigned short* __restrict__ hout) {
    __shared__ uint2 sEdge[4][64];   // .x = src idx, .y = norm bits
    int wv = threadIdx.x >> 6, lane = threadIdx.x & 63;
    int n = blockIdx.x * 4 + wv;
    if (n >= N_NODES) return;
    float dn = dinv[n];
    int deg = cnt[n]; if (deg > BUCKET) deg = BUCKET;

    uint2 s2 = ((const uint2*)(hw + (size_t)n * HIDDEN))[lane];
    float4 b4 = *(const float4*)&bias[4 * lane];
    float selfc = dn * dn;
    float a0 = bf2f(s2.x & 0xFFFFu) * selfc + b4.x;
    float a1 = bf2f(s2.x >> 16)     * selfc + b4.y;
    float a2 = bf2f(s2.y & 0xFFFFu) * selfc + b4.z;
    float a3 = bf2f(s2.y >> 16)     * selfc + b4.w;

    if (lane < deg) {
        int s = col_src[n * BUCKET + lane];
        float nr = dinv[s] * dn;
        unsigned nrb;
        __builtin_memcpy(&nrb, &nr, 4);
        sEdge[wv][lane] = make_uint2((unsigned)s, nrb);
    }
    // same-wave LDS write->read: ordered by lgkmcnt, no barrier needed
    for (int i = 0; i < deg; i++) {
        uint2 p = sEdge[wv][i];
        float nr;
        __builtin_memcpy(&nr, &p.y, 4);
        uint2 u = ((const uint2*)(hw + (size_t)p.x * HIDDEN))[lane];
        a0 += nr * bf2f(u.x & 0xFFFFu);
        a1 += nr * bf2f(u.x >> 16);
        a2 += nr * bf2f(u.y & 0xFFFFu);
        a3 += nr * bf2f(u.y >> 16);
    }
    unsigned p0 = (unsigned)f2bf(fmaxf(a0, 0.0f)) | ((unsigned)f2bf(fmaxf(a1, 0.0f)) << 16);
    unsigned p1 = (unsigned)f2bf(fmaxf(a2, 0.0f)) | ((unsigned)f2bf(fmaxf(a3, 0.0f)) << 16);
    uint2v pv; pv.x = p0; pv.y = p1;
    __builtin_nontemporal_store(pv, (uint2v*)(hout + (size_t)n * HIDDEN) + lane);
}

// ---------------- layer-4 aggregation fused with output dot (NO atomics) ----------------
// Same gather; each lane dots its 4 relu'd columns with outW, wave-reduce,
// lane 0 writes one float per node. h4 (25.6 MB) never hits global.
__global__ __launch_bounds__(256) void agg_dot_kernel(const unsigned short* __restrict__ hw,
                                                      const int* __restrict__ cnt,
                                                      const int* __restrict__ col_src,
                                                      const float* __restrict__ dinv,
                                                      const float* __restrict__ bias,
                                                      const float* __restrict__ outW,
                                                      float* __restrict__ dotv) {
    __shared__ uint2 sEdge[4][64];
    int wv = threadIdx.x >> 6, lane = threadIdx.x & 63;
    int n = blockIdx.x * 4 + wv;
    if (n >= N_NODES) return;
    float dn = dinv[n];
    int deg = cnt[n]; if (deg > BUCKET) deg = BUCKET;

    uint2 s2 = ((const uint2*)(hw + (size_t)n * HIDDEN))[lane];
    float4 b4 = *(const float4*)&bias[4 * lane];
    float selfc = dn * dn;
    float a0 = bf2f(s2.x & 0xFFFFu) * selfc + b4.x;
    float a1 = bf2f(s2.x >> 16)     * selfc + b4.y;
    float a2 = bf2f(s2.y & 0xFFFFu) * selfc + b4.z;
    float a3 = bf2f(s2.y >> 16)     * selfc + b4.w;

    if (lane < deg) {
        int s = col_src[n * BUCKET + lane];
        float nr = dinv[s] * dn;
        unsigned nrb;
        __builtin_memcpy(&nrb, &nr, 4);
        sEdge[wv][lane] = make_uint2((unsigned)s, nrb);
    }
    for (int i = 0; i < deg; i++) {
        uint2 p = sEdge[wv][i];
        float nr;
        __builtin_memcpy(&nr, &p.y, 4);
        uint2 u = ((const uint2*)(hw + (size_t)p.x * HIDDEN))[lane];
        a0 += nr * bf2f(u.x & 0xFFFFu);
        a1 += nr * bf2f(u.x >> 16);
        a2 += nr * bf2f(u.y & 0xFFFFu);
        a3 += nr * bf2f(u.y >> 16);
    }
    float4 w = *(const float4*)&outW[4 * lane];
    float dot = fmaxf(a0, 0.0f) * w.x + fmaxf(a1, 0.0f) * w.y
              + fmaxf(a2, 0.0f) * w.z + fmaxf(a3, 0.0f) * w.w;
    #pragma unroll
    for (int off = 32; off > 0; off >>= 1) dot += __shfl_xor(dot, off, 64);
    if (lane == 0) dotv[n] = dot;
}

// ---------------- segment mean over sorted batch ranges (one wave per graph) ----------------
__global__ __launch_bounds__(64) void finalize_kernel(const float* __restrict__ dotv,
                                                      const int* __restrict__ gstart,
                                                      const float* __restrict__ outb,
                                                      float* __restrict__ out) {
    int g = blockIdx.x;
    int lane = threadIdx.x;
    int s = gstart[g], e = gstart[g + 1];
    float acc = 0.0f;
    for (int n = s + lane; n < e; n += 64) acc += dotv[n];
    #pragma unroll
    for (int off = 32; off > 0; off >>= 1) acc += __shfl_xor(acc, off, 64);
    if (lane == 0) out[g] = acc / fmaxf((float)(e - s), 1.0f) + outb[0];
}

extern "C" void kernel_launch(void* const* d_in, const int* in_sizes, int n_in,
                              void* d_out, int out_size, void* d_ws, size_t ws_size,
                              hipStream_t stream) {
    const float* x     = (const float*)d_in[0];
    const int*   edge  = (const int*)d_in[1];
    const int*   src   = edge;
    const int*   dst   = edge + N_EDGES;
    const int*   batch = (const int*)d_in[2];
    const float* embW  = (const float*)d_in[3];
    const float* embb  = (const float*)d_in[4];
    const float* convW = (const float*)d_in[5];
    const float* convb = (const float*)d_in[6];
    const float* outW  = (const float*)d_in[7];
    const float* outb  = (const float*)d_in[8];
    float* out = (float*)d_out;

    // workspace layout
    char* ws = (char*)d_ws;
    size_t off = 0;
    auto take = [&](size_t bytes) { char* p = ws + off; off += (bytes + 255) & ~(size_t)255; return p; };
    int*   cnt     = (int*)  take((size_t)N_NODES * 4);
    int*   col_src = (int*)  take((size_t)N_NODES * BUCKET * 4);           // 12.8 MB buckets
    float* dinv    = (float*)take((size_t)N_NODES * 4);
    int*   gstart  = (int*)  take((size_t)(N_GRAPHS + 1) * 4);
    float* dotv    = (float*)take((size_t)N_NODES * 4);
    unsigned short* Wsw = (unsigned short*)take((size_t)LAYERS * 8 * 16 * 64 * 8 * 2); // 512 KB
    unsigned short* h0  = (unsigned short*)take((size_t)N_NODES * HIDDEN * 2);
    unsigned short* h1  = (unsigned short*)take((size_t)N_NODES * HIDDEN * 2);

    hipMemsetAsync(cnt, 0, (size_t)N_NODES * 4, stream);

    fillb_kernel<<<(N_EDGES + 255) / 256, 256, 0, stream>>>(src, dst, cnt, col_src, N_EDGES);
    dinv_kernel<<<(N_NODES + 255) / 256, 256, 0, stream>>>(cnt, dinv, N_NODES);
    findstart_kernel<<<3, 256, 0, stream>>>(batch, gstart);
    packW_kernel<<<128, 256, 0, stream>>>(convW, Wsw);

    int nblk = (N_NODES + 63) / 64;
    int ablk = (N_NODES + 3) / 4;

    // layer 1: fused embed + transform
    embed_gemm<<<nblk, 256, 0, stream>>>(x, embW, embb, Wsw, h1, N_NODES);
    agg_kernel<<<ablk, 256, 0, stream>>>(h1, cnt, col_src, dinv, convb + 0 * HIDDEN, h0);
    // layers 2..3
    gemm_mfma<<<nblk, 256, 0, stream>>>(h0, Wsw + (size_t)1 * 65536, h1, N_NODES);
    agg_kernel<<<ablk, 256, 0, stream>>>(h1, cnt, col_src, dinv, convb + 1 * HIDDEN, h0);
    gemm_mfma<<<nblk, 256, 0, stream>>>(h0, Wsw + (size_t)2 * 65536, h1, N_NODES);
    agg_kernel<<<ablk, 256, 0, stream>>>(h1, cnt, col_src, dinv, convb + 2 * HIDDEN, h0);
    // layer 4: transform, then agg fused with the output head (no h4 materialization)
    gemm_mfma<<<nblk, 256, 0, stream>>>(h0, Wsw + (size_t)3 * 65536, h1, N_NODES);
    agg_dot_kernel<<<ablk, 256, 0, stream>>>(h1, cnt, col_src, dinv, convb + 3 * HIDDEN, outW, dotv);

    finalize_kernel<<<N_GRAPHS, 64, 0, stream>>>(dotv, gstart, outb, out);
}